// Round 14
// baseline (7884.848 us; speedup 1.0000x reference)
//
#include <hip/hip_runtime.h>
#include <hip/hip_bf16.h>

#define B_ 128
#define T_ 512
#define E_ 256
#define H_ 1024
#define G_ 4096           // 4*H
#define KTOT 1280         // E + H
// s_getreg imm: size-1=31 <<11 | offset=0 <<6 | id=20 (HW_REG_XCC_ID)
#define XCC_GETREG_IMM ((31u << 11) | 20u)

typedef _Float16 f16x8 __attribute__((ext_vector_type(8)));
typedef float f32x4 __attribute__((ext_vector_type(4)));

// ---------------- JAX threefry2x32 (exact) ----------------
__device__ __forceinline__ void threefry2x32(unsigned k0, unsigned k1,
                                             unsigned x0, unsigned x1,
                                             unsigned& o0, unsigned& o1) {
  unsigned k2 = k0 ^ k1 ^ 0x1BD11BDAu;
  unsigned v0 = x0 + k0, v1 = x1 + k1;
#define RND(r) { v0 += v1; v1 = (v1 << (r)) | (v1 >> (32 - (r))); v1 ^= v0; }
  RND(13) RND(15) RND(26) RND(6)   v0 += k1; v1 += k2 + 1u;
  RND(17) RND(29) RND(16) RND(24)  v0 += k2; v1 += k0 + 2u;
  RND(13) RND(15) RND(26) RND(6)   v0 += k0; v1 += k1 + 3u;
  RND(17) RND(29) RND(16) RND(24)  v0 += k1; v1 += k2 + 4u;
  RND(13) RND(15) RND(26) RND(6)   v0 += k2; v1 += k0 + 5u;
#undef RND
  o0 = v0; o1 = v1;
}

__device__ __forceinline__ bool jax_keep(unsigned k1, unsigned i) {
  unsigned o0, o1;
  threefry2x32(0u, k1, 0u, i, o0, o1);
  unsigned bits = o0 ^ o1;
  float u = __uint_as_float((bits >> 9) | 0x3F800000u) - 1.0f;
  return u < 0.8f;
}

// ---------------- embedding + input dropout + mask ----------------
__global__ void embed_kernel(const int* __restrict__ tokens,
                             const int* __restrict__ lengths,
                             const float* __restrict__ emb,
                             _Float16* __restrict__ x) {
  unsigned i = blockIdx.x * 256u + threadIdx.x;
  if (i >= (unsigned)(B_ * T_ * E_)) return;
  int e = (int)(i & (E_ - 1));
  int t = (int)((i >> 8) & (T_ - 1));
  int b = (int)(i >> 17);
  int tok = tokens[b * T_ + t];
  float v = emb[tok * E_ + e];
  bool m = t < lengths[b];
  float xv = (m && jax_keep(1u, i)) ? (v * 1.25f) : 0.0f;
  x[i] = (_Float16)xv;
}

// ---------------- fast gate math ----------------
__device__ __forceinline__ float sigm(float v) { return 1.0f / (1.0f + __expf(-v)); }
__device__ __forceinline__ float tanh_fast(float v) {
  float c = fminf(fmaxf(v, -10.f), 10.f);
  float e = __expf(2.0f * c);
  return (e - 1.0f) / (e + 1.0f);
}

// L3-direct 16B load (full address)
#define HLD3(dst, addr) \
  asm volatile("global_load_dwordx4 %0, %1, off sc0 sc1" : "=v"(dst) : "v"(addr))
// L1-bypass, L2-cacheable 16B load (base + imm) -- staging reads
#define HLDC(dst, base, OFF) \
  asm volatile("global_load_dwordx4 %0, %1, off offset:" OFF " sc0" \
               : "=v"(dst) : "v"(base))
// h store: write-through to L3 (coherence point for all XCDs)
#define HST2(addr, val) \
  asm volatile("global_store_short %0, %1, off sc0 sc1" :: "v"(addr), "v"(val))

// ---------------- persistent bidirectional LSTM ----------------
// 128 wgs: dir = wg&1, cb = wg>>1 (16 h-cols). Per step:
//   producers: h -> L3 (sc0sc1) -> per-wg flag (system)
//   stage-A (same-XCD same-dir wgs, roster slots 0..n-1): wait 64 own-dir
//     flags at L3, pull rows {slot+j*n} L3 -> local L2 staging (normal
//     stores), local flag (agent)
//   stage-B: wait n local flags (L2), read h from staging via sc0 -> GEMM.
// No fences in the loop: L3-direct pulls + XCD-private staging = no staleness.
// sync words: [0..127] prodflags[2][64] | [128..143] roster[8][2] |
//             [144] regctr | [160 + (xcc*2+dir)*32 + slot] local flags
__global__ __launch_bounds__(512) void lstm_kernel(
    const float* __restrict__ WxF, const float* __restrict__ WhF, const float* __restrict__ bF,
    const float* __restrict__ WxB, const float* __restrict__ WhB, const float* __restrict__ bB,
    const int* __restrict__ lengths,
    const _Float16* __restrict__ x,    // [B][T][E]
    _Float16* __restrict__ hbuf,       // [dir][2][B][H]
    unsigned* __restrict__ sync,       // memset 0 per launch
    _Float16* __restrict__ staging,    // [8 xcd][2 dir][2 cur][B][H]
    float* __restrict__ out)           // [B][T][H]
{
  __shared__ _Float16 Wl[64 * KTOT];   // exactly 160 KiB

  const int wg   = blockIdx.x;        // 0..127
  const int dir  = wg & 1;
  const int cb   = wg >> 1;           // 16 h-cols [cb*16, cb*16+16)
  const int tid  = (int)threadIdx.x;
  const int lane = tid & 63;
  const int wv   = tid >> 6;

  const unsigned xcc = __builtin_amdgcn_s_getreg(XCC_GETREG_IMM) & 7u;
  unsigned* prod_own = sync + dir * 64;
  unsigned* prod_oth = sync + (dir ^ 1) * 64;
  unsigned* roster   = sync + 128;
  unsigned* regctr   = sync + 144;
  unsigned* lfbase   = sync + 160 + (xcc * 2u + (unsigned)dir) * 32u;

  // ---- registration: local slot within (xcd,dir); barrier; census ----
  if (tid == 0) {
    unsigned slot = __hip_atomic_fetch_add(&roster[xcc * 2u + (unsigned)dir], 1u,
                                           __ATOMIC_RELAXED, __HIP_MEMORY_SCOPE_SYSTEM);
    ((unsigned*)Wl)[0] = slot;
    __hip_atomic_fetch_add(regctr, 1u, __ATOMIC_RELAXED, __HIP_MEMORY_SCOPE_SYSTEM);
  }
  __syncthreads();
  const unsigned slot = ((unsigned*)Wl)[0];
  __syncthreads();
  if (tid == 0) {
    while (__hip_atomic_load(regctr, __ATOMIC_RELAXED, __HIP_MEMORY_SCOPE_SYSTEM) < 128u)
      __builtin_amdgcn_s_sleep(1);
    ((unsigned*)Wl)[0] = __hip_atomic_load(&roster[xcc * 2u + (unsigned)dir],
                                           __ATOMIC_RELAXED, __HIP_MEMORY_SCOPE_SYSTEM);
  }
  __syncthreads();
  const unsigned nloc = ((unsigned*)Wl)[0];   // same-(xcd,dir) wg count
  __syncthreads();

  const float* Wx = dir ? WxB : WxF;
  const float* Wh = dir ? WhB : WhF;
  const float* bias = dir ? bB : bF;
  _Float16* hb = hbuf + (size_t)dir * (2 * B_ * H_);
  _Float16* stag_d = staging + (size_t)(xcc * 2u + (unsigned)dir) * (2 * B_ * H_);

  // stage W, k-block interleaved: elem (c,k) -> Wl[((k>>3)*64 + c)*8 + (k&7)]
  for (int idx = tid; idx < 64 * KTOT; idx += 512) {
    int c = idx & 63, k = idx >> 6;
    int zc = ((c >> 4) << 10) + (cb << 4) + (c & 15);
    float v = (k < E_) ? Wx[k * G_ + zc] : Wh[(k - E_) * G_ + zc];
    Wl[(((k >> 3) << 6) + c) * 8 + (k & 7)] = (_Float16)v;
  }
  __syncthreads();

  const int c0   = lane & 15;
  const int q    = lane >> 4;            // 0..3
  const int ksub = q << 3;
  const int mrow = (wv << 4) + c0;       // A-frag row
  const int grow = (wv << 4) + (q << 2); // gate rows grow..grow+3
  const int hc   = (cb << 4) + c0;       // this lane's h column

  const float b_i = bias[hc], b_f = bias[1024 + hc],
              b_g = bias[2048 + hc], b_o = bias[3072 + hc];
  const int lens[4] = { lengths[grow], lengths[grow + 1],
                        lengths[grow + 2], lengths[grow + 3] };

  const _Float16* xbase = x + (size_t)mrow * T_ * E_;
  const _Float16* wq0 = Wl + (0 * 16 + c0) * 8 + q * 512;
  const _Float16* wq1 = Wl + (1 * 16 + c0) * 8 + q * 512;
  const _Float16* wq2 = Wl + (2 * 16 + c0) * 8 + q * 512;
  const _Float16* wq3 = Wl + (3 * 16 + c0) * 8 + q * 512;

#define MF4(afrag, koff) {                                                              \
    acc0 = __builtin_amdgcn_mfma_f32_16x16x32_f16(afrag, *(const f16x8*)(wq0 + (koff)), acc0, 0, 0, 0); \
    acc1 = __builtin_amdgcn_mfma_f32_16x16x32_f16(afrag, *(const f16x8*)(wq1 + (koff)), acc1, 0, 0, 0); \
    acc2 = __builtin_amdgcn_mfma_f32_16x16x32_f16(afrag, *(const f16x8*)(wq2 + (koff)), acc2, 0, 0, 0); \
    acc3 = __builtin_amdgcn_mfma_f32_16x16x32_f16(afrag, *(const f16x8*)(wq3 + (koff)), acc3, 0, 0, 0); }

  float creg[4] = {0.f, 0.f, 0.f, 0.f}, hreg[4] = {0.f, 0.f, 0.f, 0.f};

  int cur = 0;
#pragma unroll 1
  for (int s = 0; s < T_; ++s) {
    const int t = dir ? (T_ - 1 - s) : s;

    if (s == 256) {   // one-time: other dir past step 255 (its release flushed out partials)
      while (1) {
        unsigned f = __hip_atomic_load(prod_oth + lane, __ATOMIC_RELAXED, __HIP_MEMORY_SCOPE_SYSTEM);
        if (__all(f >= 256u)) break;
        __builtin_amdgcn_s_sleep(1);
      }
      __builtin_amdgcn_fence(__ATOMIC_ACQUIRE, "agent");  // one-time (safety)
    }

    float* op[4];
#pragma unroll
    for (int r = 0; r < 4; ++r)
      op[r] = out + ((size_t)(grow + r) * T_ + t) * H_ + hc;
    float oy[4] = {0.f, 0.f, 0.f, 0.f};

    f32x4 acc0 = {0.f,0.f,0.f,0.f}, acc1 = {0.f,0.f,0.f,0.f},
          acc2 = {0.f,0.f,0.f,0.f}, acc3 = {0.f,0.f,0.f,0.f};

    // x-part (k = 0..255), independent of h(s-1)
    {
      const _Float16* xr = xbase + t * E_ + ksub;
#pragma unroll
      for (int kk = 0; kk < 8; ++kk) {
        f16x8 a = *(const f16x8*)(xr + kk * 32);
        MF4(a, kk * 2048);
      }
    }
    // out-RMW operands: stable post-midpoint, off the critical chain
    if (s >= 256) {
#pragma unroll
      for (int r = 0; r < 4; ++r) oy[r] = *op[r];
    }
    __builtin_amdgcn_sched_barrier(0);

    if (s > 0) {
      const unsigned tgt = (unsigned)s;
      // ---- stage-A: wait own-dir producer flags at L3 ----
      while (1) {
        unsigned f = __hip_atomic_load(prod_own + lane, __ATOMIC_RELAXED, __HIP_MEMORY_SCOPE_SYSTEM);
        if (__all(f >= tgt)) break;
        __builtin_amdgcn_s_sleep(1);
      }
      __builtin_amdgcn_sched_barrier(0);

      // pull rows {slot + j*nloc} of h(s-1): L3 -> local-L2 staging
      const _Float16* hsrc = hb + (size_t)cur * (B_ * H_);
      _Float16* sdst = stag_d + (size_t)cur * (B_ * H_);
      {
        int nrows = (int)((127u - slot) / nloc) + 1;
        int nvec = nrows << 7;                 // 16B vectors (128 per row)
        for (int i0 = tid; i0 < nvec; i0 += 1024) {
          int i1 = i0 + 512;
          int j0 = i0 >> 7, o0 = (i0 & 127) << 3;
          int r0 = (int)slot + j0 * (int)nloc;
          f16x8 v0, v1;
          HLD3(v0, hsrc + (size_t)r0 * H_ + o0);
          bool h1 = i1 < nvec;
          int r1 = 0, o1 = 0;
          if (h1) {
            int j1 = i1 >> 7; o1 = (i1 & 127) << 3;
            r1 = (int)slot + j1 * (int)nloc;
            HLD3(v1, hsrc + (size_t)r1 * H_ + o1);
          }
          asm volatile("s_waitcnt vmcnt(0)" ::: "memory");
          *(f16x8*)(sdst + (size_t)r0 * H_ + o0) = v0;
          if (h1) *(f16x8*)(sdst + (size_t)r1 * H_ + o1) = v1;
        }
      }
      __syncthreads();                         // pull-stores acked in local L2
      if (tid == 0)
        __hip_atomic_store(lfbase + slot, tgt, __ATOMIC_RELAXED, __HIP_MEMORY_SCOPE_AGENT);

      // ---- stage-B: wait local stagers (L2 poll), then h-GEMM from L2 ----
      while (1) {
        unsigned f = tgt;
        if (lane < (int)nloc)
          f = __hip_atomic_load(lfbase + lane, __ATOMIC_RELAXED, __HIP_MEMORY_SCOPE_AGENT);
        if (__all(f >= tgt)) break;
        __builtin_amdgcn_s_sleep(1);
      }
      __builtin_amdgcn_sched_barrier(0);

      const _Float16* hr = sdst + (size_t)mrow * H_ + ksub;
      f16x8 ha[32];
      HLDC(ha[0],  hr, "0");    HLDC(ha[1],  hr, "64");   HLDC(ha[2],  hr, "128");  HLDC(ha[3],  hr, "192");
      HLDC(ha[4],  hr, "256");  HLDC(ha[5],  hr, "320");  HLDC(ha[6],  hr, "384");  HLDC(ha[7],  hr, "448");
      HLDC(ha[8],  hr, "512");  HLDC(ha[9],  hr, "576");  HLDC(ha[10], hr, "640");  HLDC(ha[11], hr, "704");
      HLDC(ha[12], hr, "768");  HLDC(ha[13], hr, "832");  HLDC(ha[14], hr, "896");  HLDC(ha[15], hr, "960");
      HLDC(ha[16], hr, "1024"); HLDC(ha[17], hr, "1088"); HLDC(ha[18], hr, "1152"); HLDC(ha[19], hr, "1216");
      HLDC(ha[20], hr, "1280"); HLDC(ha[21], hr, "1344"); HLDC(ha[22], hr, "1408"); HLDC(ha[23], hr, "1472");
      HLDC(ha[24], hr, "1536"); HLDC(ha[25], hr, "1600"); HLDC(ha[26], hr, "1664"); HLDC(ha[27], hr, "1728");
      HLDC(ha[28], hr, "1792"); HLDC(ha[29], hr, "1856"); HLDC(ha[30], hr, "1920"); HLDC(ha[31], hr, "1984");

      asm volatile("s_waitcnt vmcnt(16)" ::: "memory");
      __builtin_amdgcn_sched_barrier(0);
#pragma unroll
      for (int kk = 0; kk < 16; ++kk) MF4(ha[kk], 16384 + kk * 2048);
      asm volatile("s_waitcnt vmcnt(0)" ::: "memory");
      __builtin_amdgcn_sched_barrier(0);
#pragma unroll
      for (int kk = 16; kk < 32; ++kk) MF4(ha[kk], 16384 + kk * 2048);
    }

    // gates in-register: acc0..acc3 = (zi,zf,zg,zo)[grow+r][hc]
    float y[4];
#pragma unroll
    for (int r = 0; r < 4; ++r) {
      bool m = t < lens[r];
      float zi = acc0[r] + b_i;
      float zf = acc1[r] + b_f;
      float zg = acc2[r] + b_g;
      float zo = acc3[r] + b_o;
      float cn = sigm(zf) * creg[r] + sigm(zi) * tanh_fast(zg);
      float hn = sigm(zo) * tanh_fast(cn);
      if (m) { creg[r] = cn; hreg[r] = hn; }
      y[r] = m ? hn : 0.f;
    }

    // h write-through (4 x 2B) to L3
#pragma unroll
    for (int r = 0; r < 4; ++r) {
      _Float16 hf = (_Float16)hreg[r];
      unsigned short hu = *(unsigned short*)&hf;
      _Float16* hw = hb + (size_t)(cur ^ 1) * (B_ * H_) + (grow + r) * H_ + hc;
      HST2(hw, (unsigned)hu);
    }

    if (s == 255) {
      // midpoint producer: out partials written, then RELEASE (wbl2 -> L3)
#pragma unroll
      for (int r = 0; r < 4; ++r) *op[r] = y[r];
      __syncthreads();
      if (tid == 0)
        __hip_atomic_store(prod_own + cb, 256u, __ATOMIC_RELEASE, __HIP_MEMORY_SCOPE_SYSTEM);
    } else {
      // FAST PATH: drain h-stores (out not yet issued), publish, then lazy out
      __syncthreads();
      if (tid == 0 && s < T_ - 1)
        __hip_atomic_store(prod_own + cb, (unsigned)(s + 1), __ATOMIC_RELAXED, __HIP_MEMORY_SCOPE_SYSTEM);
      if (s < 256) {
#pragma unroll
        for (int r = 0; r < 4; ++r) *op[r] = y[r];
      } else {
#pragma unroll
        for (int r = 0; r < 4; ++r) {
          unsigned i0 = (((unsigned)(grow + r) * T_ + (unsigned)t) << 10) + (unsigned)hc;
          float f0 = oy[r] + y[r];
          *op[r] = jax_keep(2u, i0) ? f0 * 1.25f : 0.f;
        }
      }
    }
    cur ^= 1;
  }
#undef MF4
}

extern "C" void kernel_launch(void* const* d_in, const int* in_sizes, int n_in,
                              void* d_out, int out_size, void* d_ws, size_t ws_size,
                              hipStream_t stream) {
  (void)in_sizes; (void)n_in; (void)out_size; (void)ws_size;
  const int*   tokens  = (const int*)d_in[0];
  const int*   lengths = (const int*)d_in[1];
  const float* emb     = (const float*)d_in[2];
  const float* WxF     = (const float*)d_in[3];
  const float* WhF     = (const float*)d_in[4];
  const float* bF      = (const float*)d_in[5];
  const float* WxB     = (const float*)d_in[6];
  const float* WhB     = (const float*)d_in[7];
  const float* bB      = (const float*)d_in[8];
  float* out = (float*)d_out;

  _Float16* x     = (_Float16*)d_ws;                                     // 32 MB
  _Float16* hbuf  = (_Float16*)((char*)d_ws + 33554432);                 // 1 MB
  unsigned* sync  = (unsigned*)((char*)d_ws + 34603008);                 // 4 KB
  _Float16* stag  = (_Float16*)((char*)d_ws + 35651584);                 // 8 MB

  hipMemsetAsync(sync, 0, 4096, stream);

  embed_kernel<<<(B_ * T_ * E_ + 255) / 256, 256, 0, stream>>>(tokens, lengths, emb, x);

  void* args[] = { (void*)&WxF, (void*)&WhF, (void*)&bF,
                   (void*)&WxB, (void*)&WhB, (void*)&bB,
                   (void*)&lengths, (void*)&x, (void*)&hbuf, (void*)&sync,
                   (void*)&stag, (void*)&out };
  hipLaunchCooperativeKernel((const void*)lstm_kernel, dim3(128), dim3(512),
                             args, 0, stream);
}

// Round 15
// 5752.432 us; speedup vs baseline: 1.3707x; 1.3707x over previous
//
#include <hip/hip_runtime.h>
#include <hip/hip_bf16.h>

#define B_ 128
#define T_ 512
#define E_ 256
#define H_ 1024
#define G_ 4096           // 4*H
#define KTOT 1280         // E + H

typedef _Float16 f16x8 __attribute__((ext_vector_type(8)));
typedef float f32x4 __attribute__((ext_vector_type(4)));

// ---------------- JAX threefry2x32 (exact) ----------------
__device__ __forceinline__ void threefry2x32(unsigned k0, unsigned k1,
                                             unsigned x0, unsigned x1,
                                             unsigned& o0, unsigned& o1) {
  unsigned k2 = k0 ^ k1 ^ 0x1BD11BDAu;
  unsigned v0 = x0 + k0, v1 = x1 + k1;
#define RND(r) { v0 += v1; v1 = (v1 << (r)) | (v1 >> (32 - (r))); v1 ^= v0; }
  RND(13) RND(15) RND(26) RND(6)   v0 += k1; v1 += k2 + 1u;
  RND(17) RND(29) RND(16) RND(24)  v0 += k2; v1 += k0 + 2u;
  RND(13) RND(15) RND(26) RND(6)   v0 += k0; v1 += k1 + 3u;
  RND(17) RND(29) RND(16) RND(24)  v0 += k1; v1 += k2 + 4u;
  RND(13) RND(15) RND(26) RND(6)   v0 += k2; v1 += k0 + 5u;
#undef RND
  o0 = v0; o1 = v1;
}

__device__ __forceinline__ bool jax_keep(unsigned k1, unsigned i) {
  unsigned o0, o1;
  threefry2x32(0u, k1, 0u, i, o0, o1);
  unsigned bits = o0 ^ o1;
  float u = __uint_as_float((bits >> 9) | 0x3F800000u) - 1.0f;
  return u < 0.8f;
}

// ---------------- embedding + input dropout + mask ----------------
__global__ void embed_kernel(const int* __restrict__ tokens,
                             const int* __restrict__ lengths,
                             const float* __restrict__ emb,
                             _Float16* __restrict__ x) {
  unsigned i = blockIdx.x * 256u + threadIdx.x;
  if (i >= (unsigned)(B_ * T_ * E_)) return;
  int e = (int)(i & (E_ - 1));
  int t = (int)((i >> 8) & (T_ - 1));
  int b = (int)(i >> 17);
  int tok = tokens[b * T_ + t];
  float v = emb[tok * E_ + e];
  bool m = t < lengths[b];
  float xv = (m && jax_keep(1u, i)) ? (v * 1.25f) : 0.0f;
  x[i] = (_Float16)xv;
}

// ---------------- fast gate math ----------------
__device__ __forceinline__ float sigm(float v) { return 1.0f / (1.0f + __expf(-v)); }
__device__ __forceinline__ float tanh_fast(float v) {
  float c = fminf(fmaxf(v, -10.f), 10.f);
  float e = __expf(2.0f * c);
  return (e - 1.0f) / (e + 1.0f);
}

// L2-bypass 16B load / 2B store at the L3 coherence point
#define HLD(dst, base, OFF) \
  asm volatile("global_load_dwordx4 %0, %1, off offset:" OFF " sc0 sc1" \
               : "=v"(dst) : "v"(base))
#define HST2(addr, val) \
  asm volatile("global_store_short %0, %1, off sc0 sc1" :: "v"(addr), "v"(val))

#define HEAT() do { \
    _Pragma("unroll") \
    for (int z_ = 0; z_ < 8; ++z_) { \
      hx0 = __builtin_fmaf(hx0, 1.000001f, 1.0f); \
      hx1 = __builtin_fmaf(hx1, 0.999999f, 1.0f); \
    } \
    asm volatile("" :: "v"(hx0), "v"(hx1)); \
  } while (0)

// ---------------- persistent bidirectional LSTM ----------------
// 128 wgs: dir = wg&1, cb = wg>>1 owns 16 h-cols. Per-WAVE flag pipelines:
// flags[dir][wv][64] (groups 256B apart). Wave wv needs only h rows
// [16wv,16wv+16) x all cols -> polls just its group's 64 flags (1 load).
// Producer wave drains only its own 4 h-stores then lane0 publishes.
// NO __syncthreads in steady state; out stores issued lazily after publish.
__global__ __launch_bounds__(512) void lstm_kernel(
    const float* __restrict__ WxF, const float* __restrict__ WhF, const float* __restrict__ bF,
    const float* __restrict__ WxB, const float* __restrict__ WhB, const float* __restrict__ bB,
    const int* __restrict__ lengths,
    const _Float16* __restrict__ x,    // [B][T][E]
    _Float16* __restrict__ hbuf,       // [dir][2][B][H]
    unsigned* __restrict__ flags,      // [2][8][64] (memset 0)
    float* __restrict__ out)           // [B][T][H]
{
  __shared__ _Float16 Wl[64 * KTOT];   // exactly 160 KiB

  const int wg   = blockIdx.x;        // 0..127
  const int dir  = wg & 1;
  const int cb   = wg >> 1;           // 16 h-cols [cb*16, cb*16+16)
  const int tid  = (int)threadIdx.x;
  const int lane = tid & 63;
  const int wv   = tid >> 6;          // wave 0..7 == row group

  unsigned* fl_own = flags + dir * 512 + wv * 64;
  unsigned* fl_oth = flags + (dir ^ 1) * 512 + wv * 64;

  const float* Wx = dir ? WxB : WxF;
  const float* Wh = dir ? WhB : WhF;
  const float* bias = dir ? bB : bF;
  _Float16* hb = hbuf + (size_t)dir * (2 * B_ * H_);

  // stage W, k-block interleaved: elem (c,k) -> Wl[((k>>3)*64 + c)*8 + (k&7)]
  for (int idx = tid; idx < 64 * KTOT; idx += 512) {
    int c = idx & 63, k = idx >> 6;
    int zc = ((c >> 4) << 10) + (cb << 4) + (c & 15);
    float v = (k < E_) ? Wx[k * G_ + zc] : Wh[(k - E_) * G_ + zc];
    Wl[(((k >> 3) << 6) + c) * 8 + (k & 7)] = (_Float16)v;
  }
  __syncthreads();    // W ready (last wg-wide barrier before steady state)

  const int c0   = lane & 15;
  const int q    = lane >> 4;            // 0..3
  const int ksub = q << 3;
  const int mrow = (wv << 4) + c0;       // A-frag row
  const int grow = (wv << 4) + (q << 2); // gate rows grow..grow+3
  const int hc   = (cb << 4) + c0;       // this lane's h column

  const float b_i = bias[hc], b_f = bias[1024 + hc],
              b_g = bias[2048 + hc], b_o = bias[3072 + hc];
  const int lens[4] = { lengths[grow], lengths[grow + 1],
                        lengths[grow + 2], lengths[grow + 3] };

  const _Float16* xbase = x + (size_t)mrow * T_ * E_;
  const _Float16* wq0 = Wl + (0 * 16 + c0) * 8 + q * 512;
  const _Float16* wq1 = Wl + (1 * 16 + c0) * 8 + q * 512;
  const _Float16* wq2 = Wl + (2 * 16 + c0) * 8 + q * 512;
  const _Float16* wq3 = Wl + (3 * 16 + c0) * 8 + q * 512;

#define MF4(afrag, koff) {                                                              \
    acc0 = __builtin_amdgcn_mfma_f32_16x16x32_f16(afrag, *(const f16x8*)(wq0 + (koff)), acc0, 0, 0, 0); \
    acc1 = __builtin_amdgcn_mfma_f32_16x16x32_f16(afrag, *(const f16x8*)(wq1 + (koff)), acc1, 0, 0, 0); \
    acc2 = __builtin_amdgcn_mfma_f32_16x16x32_f16(afrag, *(const f16x8*)(wq2 + (koff)), acc2, 0, 0, 0); \
    acc3 = __builtin_amdgcn_mfma_f32_16x16x32_f16(afrag, *(const f16x8*)(wq3 + (koff)), acc3, 0, 0, 0); }

  float creg[4] = {0.f, 0.f, 0.f, 0.f}, hreg[4] = {0.f, 0.f, 0.f, 0.f};
  float hx0 = (float)(lane + 1), hx1 = 2.0f;

  int cur = 0;
#pragma unroll 1
  for (int s = 0; s < T_; ++s) {
    const int t = dir ? (T_ - 1 - s) : s;

    if (s == 256) {   // one-time: other dir's row-group wv past step 255 (released)
      while (1) {
        unsigned f = __hip_atomic_load(fl_oth + lane, __ATOMIC_RELAXED, __HIP_MEMORY_SCOPE_SYSTEM);
        if (__all(f >= 256u)) break;
        HEAT();
      }
      __builtin_amdgcn_fence(__ATOMIC_ACQUIRE, "agent");  // one-time inv
    }

    // prefetch out-RMW operands (stable post-midpoint; off the critical chain)
    float* op[4];
    float oy[4] = {0.f, 0.f, 0.f, 0.f};
#pragma unroll
    for (int r = 0; r < 4; ++r)
      op[r] = out + ((size_t)(grow + r) * T_ + t) * H_ + hc;
    if (s >= 256) {
#pragma unroll
      for (int r = 0; r < 4; ++r) oy[r] = *op[r];
    }

    f32x4 acc0 = {0.f,0.f,0.f,0.f}, acc1 = {0.f,0.f,0.f,0.f},
          acc2 = {0.f,0.f,0.f,0.f}, acc3 = {0.f,0.f,0.f,0.f};

    // x-part (k = 0..255), independent of h(s-1) -- overlaps the flag wait
    {
      const _Float16* xr = xbase + t * E_ + ksub;
#pragma unroll
      for (int kk = 0; kk < 8; ++kk) {
        f16x8 a = *(const f16x8*)(xr + kk * 32);
        MF4(a, kk * 2048);
      }
    }
    __builtin_amdgcn_sched_barrier(0);

    if (s > 0) {
      // wait: row-group wv of all 64 wgs of this dir completed step s-1
      const unsigned tgt = (unsigned)s;
      while (1) {
        unsigned f = __hip_atomic_load(fl_own + lane, __ATOMIC_RELAXED, __HIP_MEMORY_SCOPE_SYSTEM);
        if (__all(f >= tgt)) break;
        HEAT();
      }
      __builtin_amdgcn_sched_barrier(0);

      // h-part (k = 256..1279): L3-direct A-frags, two-phase counted waits
      const _Float16* hr = hb + (size_t)cur * (B_ * H_) + mrow * H_ + ksub;
      f16x8 ha[32];
      HLD(ha[0],  hr, "0");    HLD(ha[1],  hr, "64");   HLD(ha[2],  hr, "128");  HLD(ha[3],  hr, "192");
      HLD(ha[4],  hr, "256");  HLD(ha[5],  hr, "320");  HLD(ha[6],  hr, "384");  HLD(ha[7],  hr, "448");
      HLD(ha[8],  hr, "512");  HLD(ha[9],  hr, "576");  HLD(ha[10], hr, "640");  HLD(ha[11], hr, "704");
      HLD(ha[12], hr, "768");  HLD(ha[13], hr, "832");  HLD(ha[14], hr, "896");  HLD(ha[15], hr, "960");
      HLD(ha[16], hr, "1024"); HLD(ha[17], hr, "1088"); HLD(ha[18], hr, "1152"); HLD(ha[19], hr, "1216");
      HLD(ha[20], hr, "1280"); HLD(ha[21], hr, "1344"); HLD(ha[22], hr, "1408"); HLD(ha[23], hr, "1472");
      HLD(ha[24], hr, "1536"); HLD(ha[25], hr, "1600"); HLD(ha[26], hr, "1664"); HLD(ha[27], hr, "1728");
      HLD(ha[28], hr, "1792"); HLD(ha[29], hr, "1856"); HLD(ha[30], hr, "1920"); HLD(ha[31], hr, "1984");

      asm volatile("s_waitcnt vmcnt(16)" ::: "memory");
      __builtin_amdgcn_sched_barrier(0);
#pragma unroll
      for (int kk = 0; kk < 16; ++kk) MF4(ha[kk], 16384 + kk * 2048);
      asm volatile("s_waitcnt vmcnt(0)" ::: "memory");
      __builtin_amdgcn_sched_barrier(0);
#pragma unroll
      for (int kk = 16; kk < 32; ++kk) MF4(ha[kk], 16384 + kk * 2048);
    }

    // gates in-register: acc0..acc3 = (zi,zf,zg,zo)[grow+r][hc]
    float y[4];
#pragma unroll
    for (int r = 0; r < 4; ++r) {
      bool m = t < lens[r];
      float zi = acc0[r] + b_i;
      float zf = acc1[r] + b_f;
      float zg = acc2[r] + b_g;
      float zo = acc3[r] + b_o;
      float cn = sigm(zf) * creg[r] + sigm(zi) * tanh_fast(zg);
      float hn = sigm(zo) * tanh_fast(cn);
      if (m) { creg[r] = cn; hreg[r] = hn; }
      y[r] = m ? hn : 0.f;
    }

    // h write-through (4 x 2B) to L3
#pragma unroll
    for (int r = 0; r < 4; ++r) {
      _Float16 hf = (_Float16)hreg[r];
      unsigned short hu = *(unsigned short*)&hf;
      _Float16* hw = hb + (size_t)(cur ^ 1) * (B_ * H_) + (grow + r) * H_ + hc;
      HST2(hw, (unsigned)hu);
    }

    if (s == 255) {
      // midpoint producer (one-time, wg-wide): out partials written, all
      // waves drained, then RELEASE-publish all 8 group flags (wbl2 -> L3).
#pragma unroll
      for (int r = 0; r < 4; ++r) *op[r] = y[r];
      __syncthreads();                       // drains all waves' stores
      if (tid < 8)
        __hip_atomic_store(flags + dir * 512 + tid * 64 + cb, 256u,
                           __ATOMIC_RELEASE, __HIP_MEMORY_SCOPE_SYSTEM);
    } else {
      // FAST PATH (per-wave): drain own h-stores (out not yet issued),
      // lane0 publishes this wave's flag, then lazy out stores.
      asm volatile("s_waitcnt vmcnt(0)" ::: "memory");
      if (lane == 0 && s < T_ - 1)
        __hip_atomic_store(fl_own + cb, (unsigned)(s + 1),
                           __ATOMIC_RELAXED, __HIP_MEMORY_SCOPE_SYSTEM);
      if (s < 256) {
#pragma unroll
        for (int r = 0; r < 4; ++r) *op[r] = y[r];
      } else {
#pragma unroll
        for (int r = 0; r < 4; ++r) {
          unsigned i0 = (((unsigned)(grow + r) * T_ + (unsigned)t) << 10) + (unsigned)hc;
          float f0 = oy[r] + y[r];
          *op[r] = jax_keep(2u, i0) ? f0 * 1.25f : 0.f;
        }
      }
    }
    cur ^= 1;
  }
#undef MF4
}

extern "C" void kernel_launch(void* const* d_in, const int* in_sizes, int n_in,
                              void* d_out, int out_size, void* d_ws, size_t ws_size,
                              hipStream_t stream) {
  (void)in_sizes; (void)n_in; (void)out_size; (void)ws_size;
  const int*   tokens  = (const int*)d_in[0];
  const int*   lengths = (const int*)d_in[1];
  const float* emb     = (const float*)d_in[2];
  const float* WxF     = (const float*)d_in[3];
  const float* WhF     = (const float*)d_in[4];
  const float* bF      = (const float*)d_in[5];
  const float* WxB     = (const float*)d_in[6];
  const float* WhB     = (const float*)d_in[7];
  const float* bB      = (const float*)d_in[8];
  float* out = (float*)d_out;

  _Float16* x     = (_Float16*)d_ws;                                     // 32 MB
  _Float16* hbuf  = (_Float16*)((char*)d_ws + 33554432);                 // 1 MB
  unsigned* flags = (unsigned*)((char*)d_ws + 34603008);                 // 4 KB

  hipMemsetAsync(flags, 0, 4096, stream);

  embed_kernel<<<(B_ * T_ * E_ + 255) / 256, 256, 0, stream>>>(tokens, lengths, emb, x);

  void* args[] = { (void*)&WxF, (void*)&WhF, (void*)&bF,
                   (void*)&WxB, (void*)&WhB, (void*)&bB,
                   (void*)&lengths, (void*)&x, (void*)&hbuf, (void*)&flags, (void*)&out };
  hipLaunchCooperativeKernel((const void*)lstm_kernel, dim3(128), dim3(512),
                             args, 0, stream);
}

// Round 16
// 5364.450 us; speedup vs baseline: 1.4698x; 1.0723x over previous
//
#include <hip/hip_runtime.h>
#include <hip/hip_bf16.h>

#define B_ 128
#define T_ 512
#define E_ 256
#define H_ 1024
#define G_ 4096           // 4*H
#define KTOT 1280         // E + H

typedef _Float16 f16x8 __attribute__((ext_vector_type(8)));
typedef float f32x4 __attribute__((ext_vector_type(4)));

// ---------------- JAX threefry2x32 (exact) ----------------
__device__ __forceinline__ void threefry2x32(unsigned k0, unsigned k1,
                                             unsigned x0, unsigned x1,
                                             unsigned& o0, unsigned& o1) {
  unsigned k2 = k0 ^ k1 ^ 0x1BD11BDAu;
  unsigned v0 = x0 + k0, v1 = x1 + k1;
#define RND(r) { v0 += v1; v1 = (v1 << (r)) | (v1 >> (32 - (r))); v1 ^= v0; }
  RND(13) RND(15) RND(26) RND(6)   v0 += k1; v1 += k2 + 1u;
  RND(17) RND(29) RND(16) RND(24)  v0 += k2; v1 += k0 + 2u;
  RND(13) RND(15) RND(26) RND(6)   v0 += k0; v1 += k1 + 3u;
  RND(17) RND(29) RND(16) RND(24)  v0 += k1; v1 += k2 + 4u;
  RND(13) RND(15) RND(26) RND(6)   v0 += k2; v1 += k0 + 5u;
#undef RND
  o0 = v0; o1 = v1;
}

__device__ __forceinline__ bool jax_keep(unsigned k1, unsigned i) {
  unsigned o0, o1;
  threefry2x32(0u, k1, 0u, i, o0, o1);
  unsigned bits = o0 ^ o1;
  float u = __uint_as_float((bits >> 9) | 0x3F800000u) - 1.0f;
  return u < 0.8f;
}

// ---------------- embedding + input dropout + mask ----------------
__global__ void embed_kernel(const int* __restrict__ tokens,
                             const int* __restrict__ lengths,
                             const float* __restrict__ emb,
                             _Float16* __restrict__ x) {
  unsigned i = blockIdx.x * 256u + threadIdx.x;
  if (i >= (unsigned)(B_ * T_ * E_)) return;
  int e = (int)(i & (E_ - 1));
  int t = (int)((i >> 8) & (T_ - 1));
  int b = (int)(i >> 17);
  int tok = tokens[b * T_ + t];
  float v = emb[tok * E_ + e];
  bool m = t < lengths[b];
  float xv = (m && jax_keep(1u, i)) ? (v * 1.25f) : 0.0f;
  x[i] = (_Float16)xv;
}

// ---------------- fast gate math ----------------
__device__ __forceinline__ float sigm(float v) { return 1.0f / (1.0f + __expf(-v)); }
__device__ __forceinline__ float tanh_fast(float v) {
  float c = fminf(fmaxf(v, -10.f), 10.f);
  float e = __expf(2.0f * c);
  return (e - 1.0f) / (e + 1.0f);
}

// L2-bypass 16B load / 2B store at the L3 coherence point
#define HLD(dst, base, OFF) \
  asm volatile("global_load_dwordx4 %0, %1, off offset:" OFF " sc0 sc1" \
               : "=v"(dst) : "v"(base))
#define HST2(addr, val) \
  asm volatile("global_store_short %0, %1, off sc0 sc1" :: "v"(addr), "v"(val))

#define HEAT() do { \
    _Pragma("unroll") \
    for (int z_ = 0; z_ < 8; ++z_) { \
      hx0 = __builtin_fmaf(hx0, 1.000001f, 1.0f); \
      hx1 = __builtin_fmaf(hx1, 0.999999f, 1.0f); \
    } \
    asm volatile("" :: "v"(hx0), "v"(hx1)); \
  } while (0)

// ---------------- persistent bidirectional LSTM ----------------
// 128 wgs: dir = wg&1, cb = wg>>1 owns 16 h-cols. Per-wave flag pipelines
// flags[dir][wv][64]. GROUPED PIPELINED CONSUMER: producer cb supplies h cols
// [16cb,16cb+16) -> 4 groups of 16 producers (8 k-chunks each). Wait g ->
// issue g's loads -> vmcnt(8) -> MFMA g-1: later groups' detection + load
// latency hide under earlier groups' MFMAs. In-order vmcnt retirement makes
// the counting safe with poll loads interleaved.
__global__ __launch_bounds__(512) void lstm_kernel(
    const float* __restrict__ WxF, const float* __restrict__ WhF, const float* __restrict__ bF,
    const float* __restrict__ WxB, const float* __restrict__ WhB, const float* __restrict__ bB,
    const int* __restrict__ lengths,
    const _Float16* __restrict__ x,    // [B][T][E]
    _Float16* __restrict__ hbuf,       // [dir][2][B][H]
    unsigned* __restrict__ flags,      // [2][8][64] (memset 0)
    float* __restrict__ out)           // [B][T][H]
{
  __shared__ _Float16 Wl[64 * KTOT];   // exactly 160 KiB

  const int wg   = blockIdx.x;        // 0..127
  const int dir  = wg & 1;
  const int cb   = wg >> 1;           // 16 h-cols [cb*16, cb*16+16)
  const int tid  = (int)threadIdx.x;
  const int lane = tid & 63;
  const int wv   = tid >> 6;          // wave 0..7 == row group

  unsigned* fl_own = flags + dir * 512 + wv * 64;
  unsigned* fl_oth = flags + (dir ^ 1) * 512 + wv * 64;

  const float* Wx = dir ? WxB : WxF;
  const float* Wh = dir ? WhB : WhF;
  const float* bias = dir ? bB : bF;
  _Float16* hb = hbuf + (size_t)dir * (2 * B_ * H_);

  // stage W, k-block interleaved: elem (c,k) -> Wl[((k>>3)*64 + c)*8 + (k&7)]
  for (int idx = tid; idx < 64 * KTOT; idx += 512) {
    int c = idx & 63, k = idx >> 6;
    int zc = ((c >> 4) << 10) + (cb << 4) + (c & 15);
    float v = (k < E_) ? Wx[k * G_ + zc] : Wh[(k - E_) * G_ + zc];
    Wl[(((k >> 3) << 6) + c) * 8 + (k & 7)] = (_Float16)v;
  }
  __syncthreads();    // W ready (last wg-wide barrier before steady state)

  const int c0   = lane & 15;
  const int q    = lane >> 4;            // 0..3
  const int ksub = q << 3;
  const int mrow = (wv << 4) + c0;       // A-frag row
  const int grow = (wv << 4) + (q << 2); // gate rows grow..grow+3
  const int hc   = (cb << 4) + c0;       // this lane's h column

  const float b_i = bias[hc], b_f = bias[1024 + hc],
              b_g = bias[2048 + hc], b_o = bias[3072 + hc];
  const int lens[4] = { lengths[grow], lengths[grow + 1],
                        lengths[grow + 2], lengths[grow + 3] };

  const _Float16* xbase = x + (size_t)mrow * T_ * E_;
  const _Float16* wq0 = Wl + (0 * 16 + c0) * 8 + q * 512;
  const _Float16* wq1 = Wl + (1 * 16 + c0) * 8 + q * 512;
  const _Float16* wq2 = Wl + (2 * 16 + c0) * 8 + q * 512;
  const _Float16* wq3 = Wl + (3 * 16 + c0) * 8 + q * 512;

#define MF4(afrag, koff) {                                                              \
    acc0 = __builtin_amdgcn_mfma_f32_16x16x32_f16(afrag, *(const f16x8*)(wq0 + (koff)), acc0, 0, 0, 0); \
    acc1 = __builtin_amdgcn_mfma_f32_16x16x32_f16(afrag, *(const f16x8*)(wq1 + (koff)), acc1, 0, 0, 0); \
    acc2 = __builtin_amdgcn_mfma_f32_16x16x32_f16(afrag, *(const f16x8*)(wq2 + (koff)), acc2, 0, 0, 0); \
    acc3 = __builtin_amdgcn_mfma_f32_16x16x32_f16(afrag, *(const f16x8*)(wq3 + (koff)), acc3, 0, 0, 0); }

  float creg[4] = {0.f, 0.f, 0.f, 0.f}, hreg[4] = {0.f, 0.f, 0.f, 0.f};
  float hx0 = (float)(lane + 1), hx1 = 2.0f;

  int cur = 0;
#pragma unroll 1
  for (int s = 0; s < T_; ++s) {
    const int t = dir ? (T_ - 1 - s) : s;

    if (s == 256) {   // one-time: other dir's row-group wv past step 255 (released)
      while (1) {
        unsigned f = __hip_atomic_load(fl_oth + lane, __ATOMIC_RELAXED, __HIP_MEMORY_SCOPE_SYSTEM);
        if (__all(f >= 256u)) break;
        HEAT();
      }
      __builtin_amdgcn_fence(__ATOMIC_ACQUIRE, "agent");  // one-time inv
    }

    // prefetch out-RMW operands (stable post-midpoint; off the critical chain)
    float* op[4];
    float oy[4] = {0.f, 0.f, 0.f, 0.f};
#pragma unroll
    for (int r = 0; r < 4; ++r)
      op[r] = out + ((size_t)(grow + r) * T_ + t) * H_ + hc;
    if (s >= 256) {
#pragma unroll
      for (int r = 0; r < 4; ++r) oy[r] = *op[r];
    }

    f32x4 acc0 = {0.f,0.f,0.f,0.f}, acc1 = {0.f,0.f,0.f,0.f},
          acc2 = {0.f,0.f,0.f,0.f}, acc3 = {0.f,0.f,0.f,0.f};

    // x-part (k = 0..255), independent of h(s-1) -- overlaps the flag wait
    {
      const _Float16* xr = xbase + t * E_ + ksub;
#pragma unroll
      for (int kk = 0; kk < 8; ++kk) {
        f16x8 a = *(const f16x8*)(xr + kk * 32);
        MF4(a, kk * 2048);
      }
    }
    __builtin_amdgcn_sched_barrier(0);

    if (s > 0) {
      const unsigned tgt = (unsigned)s;
      const _Float16* hr = hb + (size_t)cur * (B_ * H_) + mrow * H_ + ksub;
      f16x8 ha[32];
      unsigned long long rdy = 0;

      // group g ready <=> producers cb in [16g,16g+16) have flag >= tgt
#define WAITG(g) \
      while ((((rdy) >> (16 * (g))) & 0xFFFFull) != 0xFFFFull) { \
        unsigned f_ = __hip_atomic_load(fl_own + lane, __ATOMIC_RELAXED, __HIP_MEMORY_SCOPE_SYSTEM); \
        rdy = __ballot(f_ >= tgt); \
        if ((((rdy) >> (16 * (g))) & 0xFFFFull) == 0xFFFFull) break; \
        HEAT(); \
      }

      WAITG(0);
      HLD(ha[0],  hr, "0");    HLD(ha[1],  hr, "64");   HLD(ha[2],  hr, "128");  HLD(ha[3],  hr, "192");
      HLD(ha[4],  hr, "256");  HLD(ha[5],  hr, "320");  HLD(ha[6],  hr, "384");  HLD(ha[7],  hr, "448");
      WAITG(1);
      HLD(ha[8],  hr, "512");  HLD(ha[9],  hr, "576");  HLD(ha[10], hr, "640");  HLD(ha[11], hr, "704");
      HLD(ha[12], hr, "768");  HLD(ha[13], hr, "832");  HLD(ha[14], hr, "896");  HLD(ha[15], hr, "960");
      asm volatile("s_waitcnt vmcnt(8)" ::: "memory");   // g0 done (8 newest = g1)
      __builtin_amdgcn_sched_barrier(0);
#pragma unroll
      for (int kk = 0; kk < 8; ++kk) MF4(ha[kk], 16384 + kk * 2048);
      WAITG(2);
      HLD(ha[16], hr, "1024"); HLD(ha[17], hr, "1088"); HLD(ha[18], hr, "1152"); HLD(ha[19], hr, "1216");
      HLD(ha[20], hr, "1280"); HLD(ha[21], hr, "1344"); HLD(ha[22], hr, "1408"); HLD(ha[23], hr, "1472");
      asm volatile("s_waitcnt vmcnt(8)" ::: "memory");   // g1 done (8 newest = g2)
      __builtin_amdgcn_sched_barrier(0);
#pragma unroll
      for (int kk = 8; kk < 16; ++kk) MF4(ha[kk], 16384 + kk * 2048);
      WAITG(3);
      HLD(ha[24], hr, "1536"); HLD(ha[25], hr, "1600"); HLD(ha[26], hr, "1664"); HLD(ha[27], hr, "1728");
      HLD(ha[28], hr, "1792"); HLD(ha[29], hr, "1856"); HLD(ha[30], hr, "1920"); HLD(ha[31], hr, "1984");
      asm volatile("s_waitcnt vmcnt(8)" ::: "memory");   // g2 done (8 newest = g3)
      __builtin_amdgcn_sched_barrier(0);
#pragma unroll
      for (int kk = 16; kk < 24; ++kk) MF4(ha[kk], 16384 + kk * 2048);
      asm volatile("s_waitcnt vmcnt(0)" ::: "memory");   // g3 done
      __builtin_amdgcn_sched_barrier(0);
#pragma unroll
      for (int kk = 24; kk < 32; ++kk) MF4(ha[kk], 16384 + kk * 2048);
#undef WAITG
    }

    // gates in-register: acc0..acc3 = (zi,zf,zg,zo)[grow+r][hc]
    float y[4];
#pragma unroll
    for (int r = 0; r < 4; ++r) {
      bool m = t < lens[r];
      float zi = acc0[r] + b_i;
      float zf = acc1[r] + b_f;
      float zg = acc2[r] + b_g;
      float zo = acc3[r] + b_o;
      float cn = sigm(zf) * creg[r] + sigm(zi) * tanh_fast(zg);
      float hn = sigm(zo) * tanh_fast(cn);
      if (m) { creg[r] = cn; hreg[r] = hn; }
      y[r] = m ? hn : 0.f;
    }

    // h write-through (4 x 2B) to L3
#pragma unroll
    for (int r = 0; r < 4; ++r) {
      _Float16 hf = (_Float16)hreg[r];
      unsigned short hu = *(unsigned short*)&hf;
      _Float16* hw = hb + (size_t)(cur ^ 1) * (B_ * H_) + (grow + r) * H_ + hc;
      HST2(hw, (unsigned)hu);
    }

    if (s == 255) {
      // midpoint producer (one-time, wg-wide): out partials written, all
      // waves drained, then RELEASE-publish all 8 group flags (wbl2 -> L3).
#pragma unroll
      for (int r = 0; r < 4; ++r) *op[r] = y[r];
      __syncthreads();                       // drains all waves' stores
      if (tid < 8)
        __hip_atomic_store(flags + dir * 512 + tid * 64 + cb, 256u,
                           __ATOMIC_RELEASE, __HIP_MEMORY_SCOPE_SYSTEM);
    } else {
      // FAST PATH (per-wave): drain own h-stores (out not yet issued),
      // lane0 publishes this wave's flag, then lazy out stores.
      asm volatile("s_waitcnt vmcnt(0)" ::: "memory");
      if (lane == 0 && s < T_ - 1)
        __hip_atomic_store(fl_own + cb, (unsigned)(s + 1),
                           __ATOMIC_RELAXED, __HIP_MEMORY_SCOPE_SYSTEM);
      if (s < 256) {
#pragma unroll
        for (int r = 0; r < 4; ++r) *op[r] = y[r];
      } else {
#pragma unroll
        for (int r = 0; r < 4; ++r) {
          unsigned i0 = (((unsigned)(grow + r) * T_ + (unsigned)t) << 10) + (unsigned)hc;
          float f0 = oy[r] + y[r];
          *op[r] = jax_keep(2u, i0) ? f0 * 1.25f : 0.f;
        }
      }
    }
    cur ^= 1;
  }
#undef MF4
}

extern "C" void kernel_launch(void* const* d_in, const int* in_sizes, int n_in,
                              void* d_out, int out_size, void* d_ws, size_t ws_size,
                              hipStream_t stream) {
  (void)in_sizes; (void)n_in; (void)out_size; (void)ws_size;
  const int*   tokens  = (const int*)d_in[0];
  const int*   lengths = (const int*)d_in[1];
  const float* emb     = (const float*)d_in[2];
  const float* WxF     = (const float*)d_in[3];
  const float* WhF     = (const float*)d_in[4];
  const float* bF      = (const float*)d_in[5];
  const float* WxB     = (const float*)d_in[6];
  const float* WhB     = (const float*)d_in[7];
  const float* bB      = (const float*)d_in[8];
  float* out = (float*)d_out;

  _Float16* x     = (_Float16*)d_ws;                                     // 32 MB
  _Float16* hbuf  = (_Float16*)((char*)d_ws + 33554432);                 // 1 MB
  unsigned* flags = (unsigned*)((char*)d_ws + 34603008);                 // 4 KB

  hipMemsetAsync(flags, 0, 4096, stream);

  embed_kernel<<<(B_ * T_ * E_ + 255) / 256, 256, 0, stream>>>(tokens, lengths, emb, x);

  void* args[] = { (void*)&WxF, (void*)&WhF, (void*)&bF,
                   (void*)&WxB, (void*)&WhB, (void*)&bB,
                   (void*)&lengths, (void*)&x, (void*)&hbuf, (void*)&flags, (void*)&out };
  hipLaunchCooperativeKernel((const void*)lstm_kernel, dim3(128), dim3(512),
                             args, 0, stream);
}